// Round 3
// baseline (2134.465 us; speedup 1.0000x reference)
//
#include <hip/hip_runtime.h>

#define PADID  100000
#define DEPS   1e-8f
#define LNEPS  1e-5f

__device__ __forceinline__ float sigm(float x) { return 1.f / (1.f + expf(-x)); }

// ---------------------------------------------------------------- transpose (f32)
__global__ void transpose_f32(const float* __restrict__ src, float* __restrict__ dst,
                              int R, int C) {
    int idx = blockIdx.x * 256 + threadIdx.x;
    if (idx < R * C) {
        int r = idx / C, c = idx - r * C;
        dst[c * R + r] = src[idx];
    }
}

// ---------------------------------------------------------------- neighbor encoder
// one block (256 thr) per (row, side). rows 0..4095 = query, 4096..4100 = support.
__global__ __launch_bounds__(256) void ne_kernel(
    const float* __restrict__ sym, const float* __restrict__ wT,
    const float* __restrict__ wbias, const float* __restrict__ gbias,
    const float* __restrict__ gate_w, const float* __restrict__ gtemp,
    const int* __restrict__ query, const int* __restrict__ support,
    const int* __restrict__ q_l1, const int* __restrict__ q_r1,
    const int* __restrict__ s_l1, const int* __restrict__ s_r1,
    const int* __restrict__ q_deg_l, const int* __restrict__ q_deg_r,
    const int* __restrict__ s_deg_l, const int* __restrict__ s_deg_r,
    float* __restrict__ qvec, float* __restrict__ svec)
{
    const int bid  = blockIdx.x;
    const int row  = bid >> 1;
    const int side = bid & 1;
    const int t    = threadIdx.x;

    const int* conn; int selfid, deg; float* out;
    if (row < 4096) {
        conn   = (side ? q_r1 : q_l1) + row * 100;
        deg    = (side ? q_deg_r : q_deg_l)[row];
        selfid = query[row * 2 + side];
        out    = qvec + row * 256 + side * 128;
    } else {
        int r  = row - 4096;
        conn   = (side ? s_r1 : s_l1) + r * 100;
        deg    = (side ? s_deg_r : s_deg_l)[r];
        selfid = support[r * 2 + side];
        out    = svec + r * 256 + side * 128;
    }

    __shared__ float s_nei[64][130];   // k-chunk of concat rows (pad rows zeroed)
    __shared__ float s_proj[50 * 130];
    __shared__ int   s_rel[50], s_ent[50];
    __shared__ float s_self[128];
    __shared__ float s_cos[64];
    __shared__ int   s_topk[10];
    __shared__ float s_misc[2];        // [0]=sum self^2  [1]=gate

    // Phase A: ids + self embedding
    if (t < 50) { s_rel[t] = conn[2 * t]; s_ent[t] = conn[2 * t + 1]; }
    if (t < 128) s_self[t] = sym[(size_t)selfid * 128 + t];
    __syncthreads();

    // Phase B/C: chunked GEMM proj[j][k] = sum_kin concat[j][kin] * wT[kin][k]
    const int tk = t & 15;   // k = tk*8 + e
    const int tj = t >> 4;   // j = tj + 16*m
    float acc[4][8];
    #pragma unroll
    for (int m = 0; m < 4; ++m)
        #pragma unroll
        for (int e = 0; e < 8; ++e) acc[m][e] = 0.f;

    for (int c = 0; c < 2; ++c) {
        for (int idx = t; idx < 64 * 128; idx += 256) {
            int j = idx >> 7, k2 = idx & 127;
            float v = 0.f;
            if (j < 50) {
                int kin = c * 128 + k2;
                int id  = (kin < 128) ? s_rel[j] : s_ent[j];
                v = sym[(size_t)id * 128 + (kin & 127)];
            }
            s_nei[j][k2] = v;
        }
        __syncthreads();
        #pragma unroll 2
        for (int k2 = 0; k2 < 128; ++k2) {
            const float* wrow = wT + (c * 128 + k2) * 128 + tk * 8;
            float4 wv0 = *(const float4*)wrow;
            float4 wv1 = *(const float4*)(wrow + 4);
            float wv[8] = {wv0.x, wv0.y, wv0.z, wv0.w, wv1.x, wv1.y, wv1.z, wv1.w};
            #pragma unroll
            for (int m = 0; m < 4; ++m) {
                float nv = s_nei[tj + m * 16][k2];
                #pragma unroll
                for (int e = 0; e < 8; ++e) acc[m][e] += nv * wv[e];
            }
        }
        __syncthreads();
    }

    // bias + leaky relu + PAD mask, store proj
    #pragma unroll
    for (int m = 0; m < 4; ++m) {
        int j = tj + m * 16;
        if (j < 50) {
            bool pad = (s_rel[j] == PADID);
            #pragma unroll
            for (int e = 0; e < 8; ++e) {
                int k = tk * 8 + e;
                float v = acc[m][e] + wbias[k] + gbias[k];
                v = (v > 0.f) ? v : 0.01f * v;
                if (pad) v = 0.f;
                s_proj[j * 130 + k] = v;
            }
        }
    }
    __syncthreads();

    // Phase D: self norm + per-neighbor cosine
    if (t < 64) {
        float a = s_self[t], b = s_self[t + 64];
        float s2 = a * a + b * b;
        #pragma unroll
        for (int off = 32; off; off >>= 1) s2 += __shfl_xor(s2, off);
        if (t == 0) s_misc[0] = s2;
    }
    __syncthreads();
    {
        int qj = t >> 2, ql = t & 3;
        if (qj < 50) {
            float num = 0.f, nn = 0.f;
            for (int k = ql; k < 128; k += 4) {
                float p = s_proj[qj * 130 + k];
                num += p * s_self[k];
                nn  += p * p;
            }
            num += __shfl_xor(num, 1); num += __shfl_xor(num, 2);
            nn  += __shfl_xor(nn, 1);  nn  += __shfl_xor(nn, 2);
            if (ql == 0) {
                float ns = sqrtf(s_misc[0] + DEPS);
                float nb = sqrtf(nn + DEPS);
                s_cos[qj] = num / (ns * nb + DEPS);
            }
        }
    }
    __syncthreads();

    // Phase E: top-10 (value desc, index asc — stable tie-break) via wave-0 argmax
    if (t < 64) {
        float myv  = (t < 50) ? s_cos[t] : -3.4e38f;
        int   live = (t < 50) ? 1 : 0;
        for (int m = 0; m < 10; ++m) {
            float bv = live ? myv : -3.4e38f;
            int   bi = t;
            #pragma unroll
            for (int off = 1; off < 64; off <<= 1) {
                float ov = __shfl_xor(bv, off);
                int   oi = __shfl_xor(bi, off);
                if (ov > bv || (ov == bv && oi < bi)) { bv = ov; bi = oi; }
            }
            if (bi == t) live = 0;
            if (t == 0) s_topk[m] = bi;
        }
    }
    // Phase F part 1: gate
    if (t < 64) {
        float g = 0.f;
        if (t < 50) {
            int r = s_rel[t];
            g = gate_w[(r == PADID) ? 0 : r];
        }
        #pragma unroll
        for (int off = 32; off; off >>= 1) g += __shfl_xor(g, off);
        if (t == 0) {
            float temp = gtemp[0];
            float gate = sigm((g / 50.f) / temp);
            if (deg <= 0) gate = 1.f;
            s_misc[1] = gate;
        }
    }
    __syncthreads();

    // Phase F part 2: agg + output
    if (t < 128) {
        float agg = 0.f;
        #pragma unroll
        for (int m = 0; m < 10; ++m) agg += s_proj[s_topk[m] * 130 + t];
        agg = agg / 10.f;
        out[t] = tanhf(s_self[t] + s_misc[1] * agg);
    }
}

// ---------------------------------------------------------------- support encoder
__global__ __launch_bounds__(256) void se_kernel(
    const float* __restrict__ qvec, const float* __restrict__ svec,
    const float* __restrict__ w1T, const float* __restrict__ w2T,
    const float* __restrict__ b1, const float* __restrict__ b2,
    const float* __restrict__ lng, const float* __restrict__ lnb,
    float* __restrict__ qenc, float* __restrict__ senc)
{
    int r = blockIdx.x, t = threadIdx.x;
    const float* x; float* o;
    if (r < 4096) { x = qvec + r * 256; o = qenc + r * 256; }
    else          { x = svec + (r - 4096) * 256; o = senc + (r - 4096) * 256; }

    __shared__ float sx[256], shid[512];
    __shared__ float ssum[4], ssq2[4];
    sx[t] = x[t];
    __syncthreads();

    // hidden = relu(x @ W1.T + b1): thread handles j = 2t, 2t+1
    {
        int j0 = 2 * t;
        float a0 = b1[j0], a1 = b1[j0 + 1];
        for (int k = 0; k < 256; ++k) {
            float xv = sx[k];
            float2 w = *(const float2*)&w1T[k * 512 + j0];
            a0 += xv * w.x;
            a1 += xv * w.y;
        }
        shid[j0]     = fmaxf(a0, 0.f);
        shid[j0 + 1] = fmaxf(a1, 0.f);
    }
    __syncthreads();

    // h = hidden @ W2.T + b2 + x, then LayerNorm
    float acc = b2[t] + sx[t];
    for (int k = 0; k < 512; ++k)
        acc += shid[k] * w2T[k * 256 + t];

    float sum = acc, sq = acc * acc;
    #pragma unroll
    for (int off = 32; off; off >>= 1) {
        sum += __shfl_xor(sum, off);
        sq  += __shfl_xor(sq,  off);
    }
    int w = t >> 6;
    if ((t & 63) == 0) { ssum[w] = sum; ssq2[w] = sq; }
    __syncthreads();
    float S = ssum[0] + ssum[1] + ssum[2] + ssum[3];
    float Q = ssq2[0] + ssq2[1] + ssq2[2] + ssq2[3];
    float mu  = S / 256.f;
    float var = Q / 256.f - mu * mu;
    o[t] = lng[t] * (acc - mu) / sqrtf(var + LNEPS) + lnb[t];
}

// ---------------------------------------------------------------- support mean + const vectors
__global__ __launch_bounds__(256) void setup_kernel(
    const float* __restrict__ senc, const float* __restrict__ Whh,
    const float* __restrict__ bih, const float* __restrict__ bhh,
    float* __restrict__ supg, float* __restrict__ supc0,
    float* __restrict__ supc, float* __restrict__ ssqp)
{
    int t = threadIdx.x;
    __shared__ float sg[256];
    __shared__ float sr[4];
    float m = (senc[t] + senc[256 + t] + senc[512 + t] + senc[768 + t] + senc[1024 + t]) * 0.2f;
    sg[t]   = m;
    supg[t] = m;
    float sq = m * m;
    #pragma unroll
    for (int off = 32; off; off >>= 1) sq += __shfl_xor(sq, off);
    if ((t & 63) == 0) sr[t >> 6] = sq;
    __syncthreads();
    if (t == 0) ssqp[0] = sr[0] + sr[1] + sr[2] + sr[3];

    for (int j = t; j < 2048; j += 256) {
        float c0 = bih[j] + bhh[j];
        float c1 = c0;
        const float* wr = Whh + (size_t)j * 512 + 256;
        for (int k = 0; k < 256; ++k) c1 += sg[k] * wr[k];
        supc0[j] = c0;   // step 0: h_r == 0
        supc[j]  = c1;   // steps 1..3: + support_g @ Whh_r.T
    }
}

// ---------------------------------------------------------------- fused LSTM step
// block = 32 rows x 32 gate-cols (x4 gates). GEMM + gate update fused.
__global__ __launch_bounds__(256) void lstm_kernel(
    const float* __restrict__ qenc, const float* __restrict__ hin,
    float* __restrict__ hout, float* __restrict__ cbuf,
    const float* __restrict__ Wih, const float* __restrict__ Whh,
    const float* __restrict__ cvec, int step)
{
    __shared__ float At[64][33];
    __shared__ float Wt[64][130];
    const int t  = threadIdx.x;
    const int tx = t & 15, ty = t >> 4;
    const int b0 = blockIdx.x * 32;
    const int j0 = blockIdx.y * 32;

    float acc[2][4][2];
    #pragma unroll
    for (int r = 0; r < 2; ++r)
        #pragma unroll
        for (int g = 0; g < 4; ++g)
            acc[r][g][0] = acc[r][g][1] = 0.f;

    for (int phase = 0; phase < 2; ++phase) {
        if (phase == 1 && step == 0) break;   // h_r == 0 at step 0
        const float* A = (phase == 0) ? qenc : hin;
        for (int kt = 0; kt < 256; kt += 64) {
            for (int idx = t; idx < 32 * 64; idx += 256) {
                int rr = idx >> 6, kk = idx & 63;
                At[kk][rr] = A[(b0 + rr) * 256 + kt + kk];
            }
            for (int idx = t; idx < 128 * 64; idx += 256) {
                int cj = idx >> 6, kk = idx & 63;
                int rowa = (cj >> 5) * 512 + j0 + (cj & 31);
                float wv;
                if (phase == 0) wv = Wih[(size_t)rowa * 256 + kt + kk];
                else            wv = Whh[(size_t)rowa * 512 + kt + kk];
                Wt[kk][cj] = wv;
            }
            __syncthreads();
            #pragma unroll 4
            for (int kk = 0; kk < 64; ++kk) {
                float a0 = At[kk][2 * ty], a1 = At[kk][2 * ty + 1];
                #pragma unroll
                for (int g = 0; g < 4; ++g) {
                    float w0 = Wt[kk][g * 32 + 2 * tx];
                    float w1 = Wt[kk][g * 32 + 2 * tx + 1];
                    acc[0][g][0] += a0 * w0; acc[0][g][1] += a0 * w1;
                    acc[1][g][0] += a1 * w0; acc[1][g][1] += a1 * w1;
                }
            }
            __syncthreads();
        }
    }

    #pragma unroll
    for (int rr = 0; rr < 2; ++rr) {
        int b = b0 + 2 * ty + rr;
        #pragma unroll
        for (int jj = 0; jj < 2; ++jj) {
            int j = j0 + 2 * tx + jj;
            float iv = acc[rr][0][jj] + cvec[j];
            float fv = acc[rr][1][jj] + cvec[512 + j];
            float gv = acc[rr][2][jj] + cvec[1024 + j];
            float ov = acc[rr][3][jj] + cvec[1536 + j];
            float cold = (step == 0) ? 0.f : cbuf[b * 512 + j];
            float cn = sigm(fv) * cold + sigm(iv) * tanhf(gv);
            cbuf[b * 512 + j] = cn;
            float hn = sigm(ov) * tanhf(cn);
            if (j < 256) hout[b * 256 + j] = qenc[b * 256 + j] + hn;
        }
    }
}

// ---------------------------------------------------------------- final cosine
__global__ __launch_bounds__(256) void final_kernel(
    const float* __restrict__ h, const float* __restrict__ supg,
    const float* __restrict__ ssqp, float* __restrict__ outp)
{
    int t = threadIdx.x;
    int w = t >> 6, l = t & 63;
    int b = blockIdx.x * 4 + w;
    float4 q = *(const float4*)&h[b * 256 + l * 4];
    float4 s = *(const float4*)&supg[l * 4];
    float num = q.x * s.x + q.y * s.y + q.z * s.z + q.w * s.w;
    float qq  = q.x * q.x + q.y * q.y + q.z * q.z + q.w * q.w;
    #pragma unroll
    for (int off = 32; off; off >>= 1) {
        num += __shfl_xor(num, off);
        qq  += __shfl_xor(qq,  off);
    }
    if (l == 0) {
        float den = sqrtf(qq + DEPS) * sqrtf(ssqp[0] + DEPS);
        outp[b] = num / den;
    }
}

// ---------------------------------------------------------------- launcher
extern "C" void kernel_launch(void* const* d_in, const int* in_sizes, int n_in,
                              void* d_out, int out_size, void* d_ws, size_t ws_size,
                              hipStream_t stream) {
    const int* query      = (const int*)d_in[0];
    const int* support    = (const int*)d_in[1];
    const int* q_l1       = (const int*)d_in[2];
    const int* q_deg_l    = (const int*)d_in[3];
    const int* q_r1       = (const int*)d_in[4];
    const int* q_deg_r    = (const int*)d_in[5];
    const int* s_l1       = (const int*)d_in[6];
    const int* s_deg_l    = (const int*)d_in[7];
    const int* s_r1       = (const int*)d_in[8];
    const int* s_deg_r    = (const int*)d_in[9];
    const float* sym      = (const float*)d_in[10];
    const float* gcn_w_W  = (const float*)d_in[11];
    const float* gcn_w_b  = (const float*)d_in[12];
    const float* gcn_b    = (const float*)d_in[13];
    const float* gate_w   = (const float*)d_in[14];
    const float* gtemp    = (const float*)d_in[15];
    const float* se_W1    = (const float*)d_in[16];
    const float* se_b1    = (const float*)d_in[17];
    const float* se_W2    = (const float*)d_in[18];
    const float* se_b2    = (const float*)d_in[19];
    const float* ln_g     = (const float*)d_in[20];
    const float* ln_b     = (const float*)d_in[21];
    const float* lstm_Wih = (const float*)d_in[22];
    const float* lstm_Whh = (const float*)d_in[23];
    const float* lstm_bih = (const float*)d_in[24];
    const float* lstm_bhh = (const float*)d_in[25];

    float* ws    = (float*)d_ws;
    float* qvec  = ws;                      // 4096*256 (aliased as h0 after se)
    float* qenc  = qvec  + 1048576;         // 4096*256
    float* h1    = qenc  + 1048576;         // 4096*256 (holds wT/w1T/w2T pre-LSTM)
    float* cbuf  = h1    + 1048576;         // 4096*512
    float* svec  = cbuf  + 2097152;         // 5*256
    float* senc  = svec  + 1280;            // 5*256
    float* supg  = senc  + 1280;            // 256
    float* supc0 = supg  + 256;             // 2048
    float* supc  = supc0 + 2048;            // 2048
    float* ssqp  = supc  + 2048;            // 1 (+3 pad)
    // transposed weights live inside h1 until LSTM step 0 overwrites it
    float* wT    = h1;                      // 256*128
    float* w1T   = h1 + 32768;              // 256*512
    float* w2T   = h1 + 163840;             // 512*256
    float* h0    = qvec;                    // alias: qvec dead after se_kernel
    // total ws use = 5249796 floats = 21.0 MB

    transpose_f32<<<128, 256, 0, stream>>>(gcn_w_W, wT, 128, 256);
    transpose_f32<<<512, 256, 0, stream>>>(se_W1, w1T, 512, 256);
    transpose_f32<<<512, 256, 0, stream>>>(se_W2, w2T, 256, 512);

    ne_kernel<<<8202, 256, 0, stream>>>(
        sym, wT, gcn_w_b, gcn_b, gate_w, gtemp,
        query, support, q_l1, q_r1, s_l1, s_r1,
        q_deg_l, q_deg_r, s_deg_l, s_deg_r, qvec, svec);

    se_kernel<<<4101, 256, 0, stream>>>(
        qvec, svec, w1T, w2T, se_b1, se_b2, ln_g, ln_b, qenc, senc);

    setup_kernel<<<1, 256, 0, stream>>>(
        senc, lstm_Whh, lstm_bih, lstm_bhh, supg, supc0, supc, ssqp);

    for (int s = 0; s < 4; ++s) {
        const float* hin = (s & 1) ? h1 : h0;   // s=0 unused
        float*      hout = (s & 1) ? h0 : h1;   // s=3 writes h0 (final)
        lstm_kernel<<<dim3(128, 16), 256, 0, stream>>>(
            qenc, hin, hout, cbuf, lstm_Wih, lstm_Whh,
            (s == 0) ? supc0 : supc, s);
    }

    final_kernel<<<1024, 256, 0, stream>>>(h0, supg, ssqp, (float*)d_out);
}

// Round 4
// 1514.146 us; speedup vs baseline: 1.4097x; 1.4097x over previous
//
#include <hip/hip_runtime.h>

#define PADID  100000
#define DEPS   1e-8f
#define LNEPS  1e-5f

__device__ __forceinline__ float sigm(float x) { return 1.f / (1.f + expf(-x)); }

// ---------------------------------------------------------------- transpose (f32)
__global__ void transpose_f32(const float* __restrict__ src, float* __restrict__ dst,
                              int R, int C) {
    int idx = blockIdx.x * 256 + threadIdx.x;
    if (idx < R * C) {
        int r = idx / C, c = idx - r * C;
        dst[c * R + r] = src[idx];
    }
}

// ---------------------------------------------------------------- neighbor encoder
// one block (256 thr) per (row, side). rows 0..4095 = query, 4096..4100 = support.
// proj kept in registers: lane(tk,tj) owns rows j=tj+16m (m<4), cols k=tk*8+e (e<8).
__global__ __launch_bounds__(256) void ne_kernel(
    const float* __restrict__ sym, const float* __restrict__ wT,
    const float* __restrict__ wbias, const float* __restrict__ gbias,
    const float* __restrict__ gate_w, const float* __restrict__ gtemp,
    const int* __restrict__ query, const int* __restrict__ support,
    const int* __restrict__ q_l1, const int* __restrict__ q_r1,
    const int* __restrict__ s_l1, const int* __restrict__ s_r1,
    const int* __restrict__ q_deg_l, const int* __restrict__ q_deg_r,
    const int* __restrict__ s_deg_l, const int* __restrict__ s_deg_r,
    float* __restrict__ qvec, float* __restrict__ svec)
{
    const int bid  = blockIdx.x;
    const int row  = bid >> 1;
    const int side = bid & 1;
    const int t    = threadIdx.x;
    const int tk   = t & 15;
    const int tj   = t >> 4;

    const int* conn; int selfid, deg; float* out;
    if (row < 4096) {
        conn   = (side ? q_r1 : q_l1) + row * 100;
        deg    = (side ? q_deg_r : q_deg_l)[row];
        selfid = query[row * 2 + side];
        out    = qvec + row * 256 + side * 128;
    } else {
        int r  = row - 4096;
        conn   = (side ? s_r1 : s_l1) + r * 100;
        deg    = (side ? s_deg_r : s_deg_l)[r];
        selfid = support[r * 2 + side];
        out    = svec + r * 256 + side * 128;
    }

    __shared__ float s_nei[64][66];     // 64 j-rows x 64-wide k-chunk (+2 pad)
    __shared__ float s_agg[16][132];    // tj-partial agg staging
    __shared__ int   s_rel[50], s_ent[50];
    __shared__ float s_self[128];
    __shared__ float s_cos[64];
    __shared__ int   s_topk[10];
    __shared__ float s_misc[2];         // [0]=sum self^2  [1]=gate

    // Phase A: ids + self embedding
    if (t < 50) { s_rel[t] = conn[2 * t]; s_ent[t] = conn[2 * t + 1]; }
    if (t < 128) s_self[t] = sym[(size_t)selfid * 128 + t];
    __syncthreads();

    // self-norm (wave 0) + per-lane self slice
    float sf[8];
    #pragma unroll
    for (int e = 0; e < 8; ++e) sf[e] = s_self[tk * 8 + e];
    if (t < 64) {
        float a = s_self[t], b = s_self[t + 64];
        float s2 = a * a + b * b;
        #pragma unroll
        for (int off = 32; off; off >>= 1) s2 += __shfl_xor(s2, off);
        if (t == 0) s_misc[0] = s2;
    }

    // Phase B/C: chunked GEMM, 4 chunks of 64 k-inputs
    float acc[4][8];
    #pragma unroll
    for (int m = 0; m < 4; ++m)
        #pragma unroll
        for (int e = 0; e < 8; ++e) acc[m][e] = 0.f;

    for (int c = 0; c < 4; ++c) {
        for (int idx = t; idx < 64 * 16; idx += 256) {
            int j = idx >> 4, k4 = (idx & 15) * 4;
            float4 v = make_float4(0.f, 0.f, 0.f, 0.f);
            if (j < 50) {
                int kin = c * 64 + k4;
                int id  = (kin < 128) ? s_rel[j] : s_ent[j];
                v = *(const float4*)&sym[(size_t)id * 128 + (kin & 127)];
            }
            *(float4*)&s_nei[j][k4] = v;
        }
        __syncthreads();
        #pragma unroll 2
        for (int k2 = 0; k2 < 64; ++k2) {
            const float* wrow = wT + (size_t)(c * 64 + k2) * 128 + tk * 8;
            float4 wv0 = *(const float4*)wrow;
            float4 wv1 = *(const float4*)(wrow + 4);
            float wv[8] = {wv0.x, wv0.y, wv0.z, wv0.w, wv1.x, wv1.y, wv1.z, wv1.w};
            #pragma unroll
            for (int m = 0; m < 4; ++m) {
                float nv = s_nei[tj + m * 16][k2];
                #pragma unroll
                for (int e = 0; e < 8; ++e) acc[m][e] += nv * wv[e];
            }
        }
        __syncthreads();
    }

    // bias + leaky relu + PAD mask (in registers)
    float wsum[8];
    #pragma unroll
    for (int e = 0; e < 8; ++e) {
        int k = tk * 8 + e;
        wsum[e] = wbias[k] + gbias[k];
    }
    #pragma unroll
    for (int m = 0; m < 4; ++m) {
        int j = tj + m * 16;
        bool dead = (j >= 50) || (s_rel[j < 50 ? j : 0] == PADID && j < 50);
        #pragma unroll
        for (int e = 0; e < 8; ++e) {
            float v = acc[m][e] + wsum[e];
            v = (v > 0.f) ? v : 0.01f * v;
            acc[m][e] = dead ? 0.f : v;
        }
    }

    // cosine per owned row: reduce over the 16 tk lanes
    {
        float ns = sqrtf(s_misc[0] + DEPS);
        #pragma unroll
        for (int m = 0; m < 4; ++m) {
            float num = 0.f, nn = 0.f;
            #pragma unroll
            for (int e = 0; e < 8; ++e) {
                float pv = acc[m][e];
                num += pv * sf[e];
                nn  += pv * pv;
            }
            #pragma unroll
            for (int off = 1; off < 16; off <<= 1) {
                num += __shfl_xor(num, off);
                nn  += __shfl_xor(nn,  off);
            }
            if (tk == 0) {
                int j = tj + m * 16;
                if (j < 50) s_cos[j] = num / (ns * sqrtf(nn + DEPS) + DEPS);
            }
        }
    }
    __syncthreads();

    // top-10 (value desc, index asc) via wave-0 argmax + gate
    if (t < 64) {
        float myv  = (t < 50) ? s_cos[t] : -3.4e38f;
        int   live = (t < 50) ? 1 : 0;
        for (int m = 0; m < 10; ++m) {
            float bv = live ? myv : -3.4e38f;
            int   bi = t;
            #pragma unroll
            for (int off = 1; off < 64; off <<= 1) {
                float ov = __shfl_xor(bv, off);
                int   oi = __shfl_xor(bi, off);
                if (ov > bv || (ov == bv && oi < bi)) { bv = ov; bi = oi; }
            }
            if (bi == t) live = 0;
            if (t == 0) s_topk[m] = bi;
        }
        float g = 0.f;
        if (t < 50) {
            int r = s_rel[t];
            g = gate_w[(r == PADID) ? 0 : r];
        }
        #pragma unroll
        for (int off = 32; off; off >>= 1) g += __shfl_xor(g, off);
        if (t == 0) {
            float gate = sigm((g / 50.f) / gtemp[0]);
            if (deg <= 0) gate = 1.f;
            s_misc[1] = gate;
        }
    }
    __syncthreads();

    // agg: each lane sums its selected rows, stage tj-partials, reduce
    {
        float ag[8];
        #pragma unroll
        for (int e = 0; e < 8; ++e) ag[e] = 0.f;
        #pragma unroll
        for (int m = 0; m < 4; ++m) {
            int j = tj + m * 16;
            bool sel = false;
            #pragma unroll
            for (int m2 = 0; m2 < 10; ++m2) sel |= (s_topk[m2] == j);
            if (sel)
                #pragma unroll
                for (int e = 0; e < 8; ++e) ag[e] += acc[m][e];
        }
        *(float4*)&s_agg[tj][tk * 8]     = make_float4(ag[0], ag[1], ag[2], ag[3]);
        *(float4*)&s_agg[tj][tk * 8 + 4] = make_float4(ag[4], ag[5], ag[6], ag[7]);
    }
    __syncthreads();

    if (t < 128) {
        float a = 0.f;
        #pragma unroll
        for (int r = 0; r < 16; ++r) a += s_agg[r][t];
        a *= 0.1f;
        out[t] = tanhf(s_self[t] + s_misc[1] * a);
    }
}

// ---------------------------------------------------------------- support encoder
// 4 rows per block: weight reads amortized 4x.
#define SE_ROWS 4
__global__ __launch_bounds__(256) void se_kernel(
    const float* __restrict__ qvec, const float* __restrict__ svec,
    const float* __restrict__ w1T, const float* __restrict__ w2T,
    const float* __restrict__ b1, const float* __restrict__ b2,
    const float* __restrict__ lng, const float* __restrict__ lnb,
    float* __restrict__ qenc, float* __restrict__ senc)
{
    const int t  = threadIdx.x;
    const int r0 = blockIdx.x * SE_ROWS;

    __shared__ float sx[SE_ROWS][256];
    __shared__ float shid[SE_ROWS][512];
    __shared__ float sred[4][SE_ROWS][2];

    for (int idx = t; idx < SE_ROWS * 64; idx += 256) {
        int r = idx >> 6, k4 = (idx & 63) * 4;
        int row = r0 + r;
        float4 v = make_float4(0.f, 0.f, 0.f, 0.f);
        if (row < 4101) {
            const float* x = (row < 4096) ? (qvec + (size_t)row * 256)
                                          : (svec + (size_t)(row - 4096) * 256);
            v = *(const float4*)&x[k4];
        }
        *(float4*)&sx[r][k4] = v;
    }
    __syncthreads();

    // phase 1: hidden = relu(x @ W1.T + b1); thread owns cols t, t+256
    float h[2][SE_ROWS];
    {
        float bb0 = b1[t], bb1 = b1[t + 256];
        #pragma unroll
        for (int r = 0; r < SE_ROWS; ++r) { h[0][r] = bb0; h[1][r] = bb1; }
    }
    for (int k = 0; k < 256; ++k) {
        float w0 = w1T[k * 512 + t];
        float w1 = w1T[k * 512 + t + 256];
        #pragma unroll
        for (int r = 0; r < SE_ROWS; ++r) {
            float xv = sx[r][k];
            h[0][r] += xv * w0;
            h[1][r] += xv * w1;
        }
    }
    #pragma unroll
    for (int r = 0; r < SE_ROWS; ++r) {
        shid[r][t]       = fmaxf(h[0][r], 0.f);
        shid[r][t + 256] = fmaxf(h[1][r], 0.f);
    }
    __syncthreads();

    // phase 2: h2 = hidden @ W2.T + b2 + x; thread owns col t
    float acc2[SE_ROWS];
    {
        float bb = b2[t];
        #pragma unroll
        for (int r = 0; r < SE_ROWS; ++r) acc2[r] = bb + sx[r][t];
    }
    for (int k = 0; k < 512; ++k) {
        float w = w2T[k * 256 + t];
        #pragma unroll
        for (int r = 0; r < SE_ROWS; ++r) acc2[r] += shid[r][k] * w;
    }

    // LayerNorm per row
    int wv = t >> 6;
    #pragma unroll
    for (int r = 0; r < SE_ROWS; ++r) {
        float s = acc2[r], q = acc2[r] * acc2[r];
        #pragma unroll
        for (int off = 32; off; off >>= 1) {
            s += __shfl_xor(s, off);
            q += __shfl_xor(q, off);
        }
        if ((t & 63) == 0) { sred[wv][r][0] = s; sred[wv][r][1] = q; }
    }
    __syncthreads();
    float gv = lng[t], bv = lnb[t];
    #pragma unroll
    for (int r = 0; r < SE_ROWS; ++r) {
        int row = r0 + r;
        if (row < 4101) {
            float S = sred[0][r][0] + sred[1][r][0] + sred[2][r][0] + sred[3][r][0];
            float Q = sred[0][r][1] + sred[1][r][1] + sred[2][r][1] + sred[3][r][1];
            float mu  = S / 256.f;
            float var = Q / 256.f - mu * mu;
            float o = gv * (acc2[r] - mu) / sqrtf(var + LNEPS) + bv;
            float* op = (row < 4096) ? (qenc + (size_t)row * 256)
                                     : (senc + (size_t)(row - 4096) * 256);
            op[t] = o;
        }
    }
}

// ---------------------------------------------------------------- support mean + const vectors
__global__ __launch_bounds__(256) void setup_kernel(
    const float* __restrict__ senc, const float* __restrict__ Whh,
    const float* __restrict__ bih, const float* __restrict__ bhh,
    float* __restrict__ supg, float* __restrict__ supc0,
    float* __restrict__ supc, float* __restrict__ ssqp)
{
    int t = threadIdx.x;
    __shared__ float sg[256];
    __shared__ float sr[4];
    float m = (senc[t] + senc[256 + t] + senc[512 + t] + senc[768 + t] + senc[1024 + t]) * 0.2f;
    sg[t]   = m;
    supg[t] = m;
    float sq = m * m;
    #pragma unroll
    for (int off = 32; off; off >>= 1) sq += __shfl_xor(sq, off);
    if ((t & 63) == 0) sr[t >> 6] = sq;
    __syncthreads();
    if (t == 0) ssqp[0] = sr[0] + sr[1] + sr[2] + sr[3];

    for (int j = t; j < 2048; j += 256) {
        float c0 = bih[j] + bhh[j];
        float c1 = c0;
        const float* wr = Whh + (size_t)j * 512 + 256;
        for (int k = 0; k < 256; ++k) c1 += sg[k] * wr[k];
        supc0[j] = c0;   // step 0: h_r == 0
        supc[j]  = c1;   // steps 1..3: + support_g @ Whh_r.T
    }
}

// ---------------------------------------------------------------- fused LSTM step
__global__ __launch_bounds__(256) void lstm_kernel(
    const float* __restrict__ qenc, const float* __restrict__ hin,
    float* __restrict__ hout, float* __restrict__ cbuf,
    const float* __restrict__ Wih, const float* __restrict__ Whh,
    const float* __restrict__ cvec, int step)
{
    __shared__ float At[64][34];
    __shared__ float Wt[64][132];
    const int t  = threadIdx.x;
    const int tx = t & 15, ty = t >> 4;
    const int b0 = blockIdx.x * 32;
    const int j0 = blockIdx.y * 32;

    float acc[2][4][2];
    #pragma unroll
    for (int r = 0; r < 2; ++r)
        #pragma unroll
        for (int g = 0; g < 4; ++g)
            acc[r][g][0] = acc[r][g][1] = 0.f;

    for (int phase = 0; phase < 2; ++phase) {
        if (phase == 1 && step == 0) break;   // h_r == 0 at step 0
        const float* A = (phase == 0) ? qenc : hin;
        for (int kt = 0; kt < 256; kt += 64) {
            for (int idx = t; idx < 32 * 64; idx += 256) {
                int rr = idx >> 6, kk = idx & 63;
                At[kk][rr] = A[(b0 + rr) * 256 + kt + kk];
            }
            for (int idx = t; idx < 128 * 64; idx += 256) {
                int cj = idx >> 6, kk = idx & 63;
                int rowa = (cj >> 5) * 512 + j0 + (cj & 31);
                float wv;
                if (phase == 0) wv = Wih[(size_t)rowa * 256 + kt + kk];
                else            wv = Whh[(size_t)rowa * 512 + kt + kk];
                Wt[kk][cj] = wv;
            }
            __syncthreads();
            #pragma unroll 4
            for (int kk = 0; kk < 64; ++kk) {
                float2 av = *(const float2*)&At[kk][2 * ty];
                #pragma unroll
                for (int g = 0; g < 4; ++g) {
                    float2 wv2 = *(const float2*)&Wt[kk][g * 32 + 2 * tx];
                    acc[0][g][0] += av.x * wv2.x; acc[0][g][1] += av.x * wv2.y;
                    acc[1][g][0] += av.y * wv2.x; acc[1][g][1] += av.y * wv2.y;
                }
            }
            __syncthreads();
        }
    }

    #pragma unroll
    for (int rr = 0; rr < 2; ++rr) {
        int b = b0 + 2 * ty + rr;
        #pragma unroll
        for (int jj = 0; jj < 2; ++jj) {
            int j = j0 + 2 * tx + jj;
            float iv = acc[rr][0][jj] + cvec[j];
            float fv = acc[rr][1][jj] + cvec[512 + j];
            float gv = acc[rr][2][jj] + cvec[1024 + j];
            float ov = acc[rr][3][jj] + cvec[1536 + j];
            float cold = (step == 0) ? 0.f : cbuf[b * 512 + j];
            float cn = sigm(fv) * cold + sigm(iv) * tanhf(gv);
            cbuf[b * 512 + j] = cn;
            float hn = sigm(ov) * tanhf(cn);
            if (j < 256) hout[b * 256 + j] = qenc[b * 256 + j] + hn;
        }
    }
}

// ---------------------------------------------------------------- final cosine
__global__ __launch_bounds__(256) void final_kernel(
    const float* __restrict__ h, const float* __restrict__ supg,
    const float* __restrict__ ssqp, float* __restrict__ outp)
{
    int t = threadIdx.x;
    int w = t >> 6, l = t & 63;
    int b = blockIdx.x * 4 + w;
    float4 q = *(const float4*)&h[b * 256 + l * 4];
    float4 s = *(const float4*)&supg[l * 4];
    float num = q.x * s.x + q.y * s.y + q.z * s.z + q.w * s.w;
    float qq  = q.x * q.x + q.y * q.y + q.z * q.z + q.w * q.w;
    #pragma unroll
    for (int off = 32; off; off >>= 1) {
        num += __shfl_xor(num, off);
        qq  += __shfl_xor(qq,  off);
    }
    if (l == 0) {
        float den = sqrtf(qq + DEPS) * sqrtf(ssqp[0] + DEPS);
        outp[b] = num / den;
    }
}

// ---------------------------------------------------------------- launcher
extern "C" void kernel_launch(void* const* d_in, const int* in_sizes, int n_in,
                              void* d_out, int out_size, void* d_ws, size_t ws_size,
                              hipStream_t stream) {
    const int* query      = (const int*)d_in[0];
    const int* support    = (const int*)d_in[1];
    const int* q_l1       = (const int*)d_in[2];
    const int* q_deg_l    = (const int*)d_in[3];
    const int* q_r1       = (const int*)d_in[4];
    const int* q_deg_r    = (const int*)d_in[5];
    const int* s_l1       = (const int*)d_in[6];
    const int* s_deg_l    = (const int*)d_in[7];
    const int* s_r1       = (const int*)d_in[8];
    const int* s_deg_r    = (const int*)d_in[9];
    const float* sym      = (const float*)d_in[10];
    const float* gcn_w_W  = (const float*)d_in[11];
    const float* gcn_w_b  = (const float*)d_in[12];
    const float* gcn_b    = (const float*)d_in[13];
    const float* gate_w   = (const float*)d_in[14];
    const float* gtemp    = (const float*)d_in[15];
    const float* se_W1    = (const float*)d_in[16];
    const float* se_b1    = (const float*)d_in[17];
    const float* se_W2    = (const float*)d_in[18];
    const float* se_b2    = (const float*)d_in[19];
    const float* ln_g     = (const float*)d_in[20];
    const float* ln_b     = (const float*)d_in[21];
    const float* lstm_Wih = (const float*)d_in[22];
    const float* lstm_Whh = (const float*)d_in[23];
    const float* lstm_bih = (const float*)d_in[24];
    const float* lstm_bhh = (const float*)d_in[25];

    float* ws    = (float*)d_ws;
    float* qvec  = ws;                      // 4096*256 (aliased as h0 after se)
    float* qenc  = qvec  + 1048576;         // 4096*256
    float* h1    = qenc  + 1048576;         // 4096*256 (holds wT/w1T/w2T pre-LSTM)
    float* cbuf  = h1    + 1048576;         // 4096*512
    float* svec  = cbuf  + 2097152;         // 5*256
    float* senc  = svec  + 1280;            // 5*256
    float* supg  = senc  + 1280;            // 256
    float* supc0 = supg  + 256;             // 2048
    float* supc  = supc0 + 2048;            // 2048
    float* ssqp  = supc  + 2048;            // 1 (+3 pad)
    // transposed weights live inside h1 until LSTM step 0 overwrites it
    float* wT    = h1;                      // 256*128
    float* w1T   = h1 + 32768;              // 256*512
    float* w2T   = h1 + 163840;             // 512*256
    float* h0    = qvec;                    // alias: qvec dead after se_kernel

    transpose_f32<<<128, 256, 0, stream>>>(gcn_w_W, wT, 128, 256);
    transpose_f32<<<512, 256, 0, stream>>>(se_W1, w1T, 512, 256);
    transpose_f32<<<512, 256, 0, stream>>>(se_W2, w2T, 256, 512);

    ne_kernel<<<8202, 256, 0, stream>>>(
        sym, wT, gcn_w_b, gcn_b, gate_w, gtemp,
        query, support, q_l1, q_r1, s_l1, s_r1,
        q_deg_l, q_deg_r, s_deg_l, s_deg_r, qvec, svec);

    se_kernel<<<1026, 256, 0, stream>>>(
        qvec, svec, w1T, w2T, se_b1, se_b2, ln_g, ln_b, qenc, senc);

    setup_kernel<<<1, 256, 0, stream>>>(
        senc, lstm_Whh, lstm_bih, lstm_bhh, supg, supc0, supc, ssqp);

    for (int s = 0; s < 4; ++s) {
        const float* hin = (s & 1) ? h1 : h0;   // s=0 unused
        float*      hout = (s & 1) ? h0 : h1;   // s=3 writes h0 (final)
        lstm_kernel<<<dim3(128, 16), 256, 0, stream>>>(
            qenc, hin, hout, cbuf, lstm_Wih, lstm_Whh,
            (s == 0) ? supc0 : supc, s);
    }

    final_kernel<<<1024, 256, 0, stream>>>(h0, supg, ssqp, (float*)d_out);
}

// Round 5
// 847.061 us; speedup vs baseline: 2.5198x; 1.7875x over previous
//
#include <hip/hip_runtime.h>

#define PADID  100000
#define DEPS   1e-8f
#define LNEPS  1e-5f

typedef unsigned short u16;
typedef unsigned int u32;
typedef __attribute__((ext_vector_type(8))) short s16x8;   // 8 bf16 = 4 VGPR
typedef __attribute__((ext_vector_type(4))) float f32x4;

__device__ __forceinline__ float sigm(float x) { return 1.f / (1.f + expf(-x)); }
__device__ __forceinline__ float bf2f(u16 v) { return __uint_as_float(((u32)v) << 16); }
__device__ __forceinline__ u16 f2bf(float f) {            // RNE f32->bf16
    u32 x = __float_as_uint(f);
    x += 0x7FFFu + ((x >> 16) & 1u);
    return (u16)(x >> 16);
}

// ---------------------------------------------------------------- transpose (f32)
__global__ void transpose_f32(const float* __restrict__ src, float* __restrict__ dst,
                              int R, int C) {
    int idx = blockIdx.x * 256 + threadIdx.x;
    if (idx < R * C) {
        int r = idx / C, c = idx - r * C;
        dst[c * R + r] = src[idx];
    }
}

// ---------------------------------------------------------------- neighbor encoder
// one block (256 thr) per (row, side). rows 0..4095 = query, 4096..4100 = support.
__global__ __launch_bounds__(256) void ne_kernel(
    const float* __restrict__ sym, const float* __restrict__ wT,
    const float* __restrict__ wbias, const float* __restrict__ gbias,
    const float* __restrict__ gate_w, const float* __restrict__ gtemp,
    const int* __restrict__ query, const int* __restrict__ support,
    const int* __restrict__ q_l1, const int* __restrict__ q_r1,
    const int* __restrict__ s_l1, const int* __restrict__ s_r1,
    const int* __restrict__ q_deg_l, const int* __restrict__ q_deg_r,
    const int* __restrict__ s_deg_l, const int* __restrict__ s_deg_r,
    float* __restrict__ qvec, float* __restrict__ svec)
{
    const int bid  = blockIdx.x;
    const int row  = bid >> 1;
    const int side = bid & 1;
    const int t    = threadIdx.x;
    const int tk   = t & 15;
    const int tj   = t >> 4;

    const int* conn; int selfid, deg; float* out;
    if (row < 4096) {
        conn   = (side ? q_r1 : q_l1) + row * 100;
        deg    = (side ? q_deg_r : q_deg_l)[row];
        selfid = query[row * 2 + side];
        out    = qvec + row * 256 + side * 128;
    } else {
        int r  = row - 4096;
        conn   = (side ? s_r1 : s_l1) + r * 100;
        deg    = (side ? s_deg_r : s_deg_l)[r];
        selfid = support[r * 2 + side];
        out    = svec + r * 256 + side * 128;
    }

    __shared__ float s_nei[64][66];
    __shared__ float s_agg[16][132];
    __shared__ int   s_rel[50], s_ent[50];
    __shared__ float s_self[128];
    __shared__ float s_cos[64];
    __shared__ int   s_topk[10];
    __shared__ float s_misc[2];

    if (t < 50) { s_rel[t] = conn[2 * t]; s_ent[t] = conn[2 * t + 1]; }
    if (t < 128) s_self[t] = sym[(size_t)selfid * 128 + t];
    __syncthreads();

    float sf[8];
    #pragma unroll
    for (int e = 0; e < 8; ++e) sf[e] = s_self[tk * 8 + e];
    if (t < 64) {
        float a = s_self[t], b = s_self[t + 64];
        float s2 = a * a + b * b;
        #pragma unroll
        for (int off = 32; off; off >>= 1) s2 += __shfl_xor(s2, off);
        if (t == 0) s_misc[0] = s2;
    }

    float acc[4][8];
    #pragma unroll
    for (int m = 0; m < 4; ++m)
        #pragma unroll
        for (int e = 0; e < 8; ++e) acc[m][e] = 0.f;

    for (int c = 0; c < 4; ++c) {
        for (int idx = t; idx < 64 * 16; idx += 256) {
            int j = idx >> 4, k4 = (idx & 15) * 4;
            float4 v = make_float4(0.f, 0.f, 0.f, 0.f);
            if (j < 50) {
                int kin = c * 64 + k4;
                int id  = (kin < 128) ? s_rel[j] : s_ent[j];
                v = *(const float4*)&sym[(size_t)id * 128 + (kin & 127)];
            }
            *(float4*)&s_nei[j][k4] = v;
        }
        __syncthreads();
        #pragma unroll 2
        for (int k2 = 0; k2 < 64; ++k2) {
            const float* wrow = wT + (size_t)(c * 64 + k2) * 128 + tk * 8;
            float4 wv0 = *(const float4*)wrow;
            float4 wv1 = *(const float4*)(wrow + 4);
            float wv[8] = {wv0.x, wv0.y, wv0.z, wv0.w, wv1.x, wv1.y, wv1.z, wv1.w};
            #pragma unroll
            for (int m = 0; m < 4; ++m) {
                float nv = s_nei[tj + m * 16][k2];
                #pragma unroll
                for (int e = 0; e < 8; ++e) acc[m][e] += nv * wv[e];
            }
        }
        __syncthreads();
    }

    float wsum[8];
    #pragma unroll
    for (int e = 0; e < 8; ++e) {
        int k = tk * 8 + e;
        wsum[e] = wbias[k] + gbias[k];
    }
    #pragma unroll
    for (int m = 0; m < 4; ++m) {
        int j = tj + m * 16;
        bool dead = (j >= 50) || (s_rel[j < 50 ? j : 0] == PADID && j < 50);
        #pragma unroll
        for (int e = 0; e < 8; ++e) {
            float v = acc[m][e] + wsum[e];
            v = (v > 0.f) ? v : 0.01f * v;
            acc[m][e] = dead ? 0.f : v;
        }
    }

    {
        float ns = sqrtf(s_misc[0] + DEPS);
        #pragma unroll
        for (int m = 0; m < 4; ++m) {
            float num = 0.f, nn = 0.f;
            #pragma unroll
            for (int e = 0; e < 8; ++e) {
                float pv = acc[m][e];
                num += pv * sf[e];
                nn  += pv * pv;
            }
            #pragma unroll
            for (int off = 1; off < 16; off <<= 1) {
                num += __shfl_xor(num, off);
                nn  += __shfl_xor(nn,  off);
            }
            if (tk == 0) {
                int j = tj + m * 16;
                if (j < 50) s_cos[j] = num / (ns * sqrtf(nn + DEPS) + DEPS);
            }
        }
    }
    __syncthreads();

    if (t < 64) {
        float myv  = (t < 50) ? s_cos[t] : -3.4e38f;
        int   live = (t < 50) ? 1 : 0;
        for (int m = 0; m < 10; ++m) {
            float bv = live ? myv : -3.4e38f;
            int   bi = t;
            #pragma unroll
            for (int off = 1; off < 64; off <<= 1) {
                float ov = __shfl_xor(bv, off);
                int   oi = __shfl_xor(bi, off);
                if (ov > bv || (ov == bv && oi < bi)) { bv = ov; bi = oi; }
            }
            if (bi == t) live = 0;
            if (t == 0) s_topk[m] = bi;
        }
        float g = 0.f;
        if (t < 50) {
            int r = s_rel[t];
            g = gate_w[(r == PADID) ? 0 : r];
        }
        #pragma unroll
        for (int off = 32; off; off >>= 1) g += __shfl_xor(g, off);
        if (t == 0) {
            float gate = sigm((g / 50.f) / gtemp[0]);
            if (deg <= 0) gate = 1.f;
            s_misc[1] = gate;
        }
    }
    __syncthreads();

    {
        float ag[8];
        #pragma unroll
        for (int e = 0; e < 8; ++e) ag[e] = 0.f;
        #pragma unroll
        for (int m = 0; m < 4; ++m) {
            int j = tj + m * 16;
            bool sel = false;
            #pragma unroll
            for (int m2 = 0; m2 < 10; ++m2) sel |= (s_topk[m2] == j);
            if (sel)
                #pragma unroll
                for (int e = 0; e < 8; ++e) ag[e] += acc[m][e];
        }
        *(float4*)&s_agg[tj][tk * 8]     = make_float4(ag[0], ag[1], ag[2], ag[3]);
        *(float4*)&s_agg[tj][tk * 8 + 4] = make_float4(ag[4], ag[5], ag[6], ag[7]);
    }
    __syncthreads();

    if (t < 128) {
        float a = 0.f;
        #pragma unroll
        for (int r = 0; r < 16; ++r) a += s_agg[r][t];
        a *= 0.1f;
        out[t] = tanhf(s_self[t] + s_misc[1] * a);
    }
}

// ---------------------------------------------------------------- support encoder
#define SE_ROWS 4
__global__ __launch_bounds__(256) void se_kernel(
    const float* __restrict__ qvec, const float* __restrict__ svec,
    const float* __restrict__ w1T, const float* __restrict__ w2T,
    const float* __restrict__ b1, const float* __restrict__ b2,
    const float* __restrict__ lng, const float* __restrict__ lnb,
    float* __restrict__ qenc, float* __restrict__ senc)
{
    const int t  = threadIdx.x;
    const int r0 = blockIdx.x * SE_ROWS;

    __shared__ float sx[SE_ROWS][256];
    __shared__ float shid[SE_ROWS][512];
    __shared__ float sred[4][SE_ROWS][2];

    for (int idx = t; idx < SE_ROWS * 64; idx += 256) {
        int r = idx >> 6, k4 = (idx & 63) * 4;
        int row = r0 + r;
        float4 v = make_float4(0.f, 0.f, 0.f, 0.f);
        if (row < 4101) {
            const float* x = (row < 4096) ? (qvec + (size_t)row * 256)
                                          : (svec + (size_t)(row - 4096) * 256);
            v = *(const float4*)&x[k4];
        }
        *(float4*)&sx[r][k4] = v;
    }
    __syncthreads();

    float h[2][SE_ROWS];
    {
        float bb0 = b1[t], bb1 = b1[t + 256];
        #pragma unroll
        for (int r = 0; r < SE_ROWS; ++r) { h[0][r] = bb0; h[1][r] = bb1; }
    }
    for (int k = 0; k < 256; ++k) {
        float w0 = w1T[k * 512 + t];
        float w1 = w1T[k * 512 + t + 256];
        #pragma unroll
        for (int r = 0; r < SE_ROWS; ++r) {
            float xv = sx[r][k];
            h[0][r] += xv * w0;
            h[1][r] += xv * w1;
        }
    }
    #pragma unroll
    for (int r = 0; r < SE_ROWS; ++r) {
        shid[r][t]       = fmaxf(h[0][r], 0.f);
        shid[r][t + 256] = fmaxf(h[1][r], 0.f);
    }
    __syncthreads();

    float acc2[SE_ROWS];
    {
        float bb = b2[t];
        #pragma unroll
        for (int r = 0; r < SE_ROWS; ++r) acc2[r] = bb + sx[r][t];
    }
    for (int k = 0; k < 512; ++k) {
        float w = w2T[k * 256 + t];
        #pragma unroll
        for (int r = 0; r < SE_ROWS; ++r) acc2[r] += shid[r][k] * w;
    }

    int wv = t >> 6;
    #pragma unroll
    for (int r = 0; r < SE_ROWS; ++r) {
        float s = acc2[r], q = acc2[r] * acc2[r];
        #pragma unroll
        for (int off = 32; off; off >>= 1) {
            s += __shfl_xor(s, off);
            q += __shfl_xor(q, off);
        }
        if ((t & 63) == 0) { sred[wv][r][0] = s; sred[wv][r][1] = q; }
    }
    __syncthreads();
    float gv = lng[t], bv = lnb[t];
    #pragma unroll
    for (int r = 0; r < SE_ROWS; ++r) {
        int row = r0 + r;
        if (row < 4101) {
            float S = sred[0][r][0] + sred[1][r][0] + sred[2][r][0] + sred[3][r][0];
            float Q = sred[0][r][1] + sred[1][r][1] + sred[2][r][1] + sred[3][r][1];
            float mu  = S / 256.f;
            float var = Q / 256.f - mu * mu;
            float o = gv * (acc2[r] - mu) / sqrtf(var + LNEPS) + bv;
            float* op = (row < 4096) ? (qenc + (size_t)row * 256)
                                     : (senc + (size_t)(row - 4096) * 256);
            op[t] = o;
        }
    }
}

// ---------------------------------------------------------------- support mean
__global__ __launch_bounds__(256) void supg_kernel(
    const float* __restrict__ senc, float* __restrict__ supg,
    float* __restrict__ ssqp)
{
    int t = threadIdx.x;
    __shared__ float sr[4];
    float m = (senc[t] + senc[256 + t] + senc[512 + t] + senc[768 + t] + senc[1024 + t]) * 0.2f;
    supg[t] = m;
    float sq = m * m;
    #pragma unroll
    for (int off = 32; off; off >>= 1) sq += __shfl_xor(sq, off);
    if ((t & 63) == 0) sr[t >> 6] = sq;
    __syncthreads();
    if (t == 0) ssqp[0] = sr[0] + sr[1] + sr[2] + sr[3];
}

// ---------------------------------------------------------------- supc: cvec = bih+bhh (+ supg @ Whh_r.T)
// 32 blocks x 4 waves; each wave computes 16 j's (lane-parallel dot over k).
__global__ __launch_bounds__(256) void supc_kernel(
    const float* __restrict__ supg, const float* __restrict__ Whh,
    const float* __restrict__ bih, const float* __restrict__ bhh,
    float* __restrict__ supc0, float* __restrict__ supc)
{
    const int t = threadIdx.x, w = t >> 6, l = t & 63;
    __shared__ float sg[256];
    if (t < 256) sg[t] = supg[t];
    __syncthreads();
    float4 gv = *(const float4*)&sg[l * 4];
    #pragma unroll
    for (int jj = 0; jj < 16; ++jj) {
        int j = blockIdx.x * 64 + w * 16 + jj;
        float4 wv = *(const float4*)&Whh[(size_t)j * 512 + 256 + l * 4];
        float p = gv.x * wv.x + gv.y * wv.y + gv.z * wv.z + gv.w * wv.w;
        #pragma unroll
        for (int off = 32; off; off >>= 1) p += __shfl_xor(p, off);
        if (l == 0) {
            float c0 = bih[j] + bhh[j];
            supc0[j] = c0;
            supc[j]  = c0 + p;
        }
    }
}

// ---------------------------------------------------------------- bf16 prep: Abf[:, :256]=qenc, Wcat=[Wih | WhhL]
__global__ __launch_bounds__(256) void prep_kernel(
    const float* __restrict__ qenc, const float* __restrict__ Wih,
    const float* __restrict__ Whh, u16* __restrict__ Abf, u16* __restrict__ Wcat)
{
    int idx = blockIdx.x * 256 + threadIdx.x;
    // 4096*256 qenc + 2048*256 Wih + 2048*256 WhhL = 2,097,152 threads exactly
    if (idx < 1048576) {
        int m = idx >> 8, k = idx & 255;
        Abf[(size_t)m * 512 + k] = f2bf(qenc[idx]);
    } else if (idx < 1572864) {
        int i = idx - 1048576;
        int n = i >> 8, k = i & 255;
        Wcat[(size_t)n * 512 + k] = f2bf(Wih[i]);
    } else {
        int i = idx - 1572864;
        int n = i >> 8, k = i & 255;
        Wcat[(size_t)n * 512 + 256 + k] = f2bf(Whh[(size_t)n * 512 + k]);
    }
}

// ---------------------------------------------------------------- LSTM gate GEMM (bf16 MFMA)
// gates[4096x2048] = Abf[4096xK] @ Wcat[2048xK]^T   (K = 256 step0, else 512)
// block 64x64, 4 waves each 32x32 (2x2 MFMA 16x16x32 tiles).
__global__ __launch_bounds__(256) void lstm_mfma(
    const u16* __restrict__ A, const u16* __restrict__ B,
    u16* __restrict__ C, int Klen)
{
    __shared__ u16 sA[64][72];   // 144B row stride: 16B-aligned, 2-way max conflicts
    __shared__ u16 sB[64][72];
    const int t    = threadIdx.x;
    const int wid  = t >> 6;
    const int lane = t & 63;
    const int m0   = blockIdx.x * 64;
    const int n0   = blockIdx.y * 64;
    const int mw   = (wid & 1) * 32;
    const int nw   = (wid >> 1) * 32;
    const int r    = t >> 2;          // staging row 0..63
    const int q    = t & 3;           // staging k-quarter (16 bf16 each)
    const int fr   = lane & 15;       // fragment row/col
    const int fk   = (lane >> 4) * 8; // fragment k-offset

    f32x4 acc[2][2];
    #pragma unroll
    for (int i = 0; i < 2; ++i)
        #pragma unroll
        for (int j = 0; j < 2; ++j)
            acc[i][j] = (f32x4){0.f, 0.f, 0.f, 0.f};

    for (int k0 = 0; k0 < Klen; k0 += 64) {
        const u16* ga = A + (size_t)(m0 + r) * 512 + k0 + q * 16;
        const u16* gb = B + (size_t)(n0 + r) * 512 + k0 + q * 16;
        uint4 va0 = *(const uint4*)ga;
        uint4 va1 = *(const uint4*)(ga + 8);
        uint4 vb0 = *(const uint4*)gb;
        uint4 vb1 = *(const uint4*)(gb + 8);
        __syncthreads();   // previous iteration's frag reads complete
        *(uint4*)&sA[r][q * 16]     = va0;
        *(uint4*)&sA[r][q * 16 + 8] = va1;
        *(uint4*)&sB[r][q * 16]     = vb0;
        *(uint4*)&sB[r][q * 16 + 8] = vb1;
        __syncthreads();
        #pragma unroll
        for (int ks = 0; ks < 64; ks += 32) {
            s16x8 af[2], bf[2];
            #pragma unroll
            for (int i = 0; i < 2; ++i)
                af[i] = *(const s16x8*)&sA[mw + i * 16 + fr][ks + fk];
            #pragma unroll
            for (int j = 0; j < 2; ++j)
                bf[j] = *(const s16x8*)&sB[nw + j * 16 + fr][ks + fk];
            #pragma unroll
            for (int i = 0; i < 2; ++i)
                #pragma unroll
                for (int j = 0; j < 2; ++j)
                    acc[i][j] = __builtin_amdgcn_mfma_f32_16x16x32_bf16(
                        af[i], bf[j], acc[i][j], 0, 0, 0);
        }
    }

    // C/D layout: col = lane&15, row = (lane>>4)*4 + reg  [HW-verified]
    #pragma unroll
    for (int i = 0; i < 2; ++i)
        #pragma unroll
        for (int j = 0; j < 2; ++j) {
            int col = n0 + nw + j * 16 + fr;
            #pragma unroll
            for (int rr = 0; rr < 4; ++rr) {
                int rowi = m0 + mw + i * 16 + (lane >> 4) * 4 + rr;
                C[(size_t)rowi * 2048 + col] = f2bf(acc[i][j][rr]);
            }
        }
}

// ---------------------------------------------------------------- LSTM elementwise
__global__ __launch_bounds__(256) void lstm_elem(
    const u16* __restrict__ gates, const float* __restrict__ cvec,
    float* __restrict__ cbuf, const float* __restrict__ qenc,
    u16* __restrict__ Abf, float* __restrict__ hfinal, int step)
{
    int idx = blockIdx.x * 256 + threadIdx.x;     // 4096*512
    int m = idx >> 9, j = idx & 511;
    const u16* g = gates + (size_t)m * 2048;
    float iv = bf2f(g[j])        + cvec[j];
    float fv = bf2f(g[512 + j])  + cvec[512 + j];
    float gv = bf2f(g[1024 + j]) + cvec[1024 + j];
    float ov = bf2f(g[1536 + j]) + cvec[1536 + j];
    float cold = (step == 0) ? 0.f : cbuf[idx];
    float cn = sigm(fv) * cold + sigm(iv) * tanhf(gv);
    cbuf[idx] = cn;
    if (j < 256) {
        float hn = sigm(ov) * tanhf(cn);
        float h  = qenc[(size_t)m * 256 + j] + hn;
        Abf[(size_t)m * 512 + 256 + j] = f2bf(h);
        if (step == 3) hfinal[(size_t)m * 256 + j] = h;
    }
}

// ---------------------------------------------------------------- final cosine
__global__ __launch_bounds__(256) void final_kernel(
    const float* __restrict__ h, const float* __restrict__ supg,
    const float* __restrict__ ssqp, float* __restrict__ outp)
{
    int t = threadIdx.x;
    int w = t >> 6, l = t & 63;
    int b = blockIdx.x * 4 + w;
    float4 q = *(const float4*)&h[b * 256 + l * 4];
    float4 s = *(const float4*)&supg[l * 4];
    float num = q.x * s.x + q.y * s.y + q.z * s.z + q.w * s.w;
    float qq  = q.x * q.x + q.y * q.y + q.z * q.z + q.w * q.w;
    #pragma unroll
    for (int off = 32; off; off >>= 1) {
        num += __shfl_xor(num, off);
        qq  += __shfl_xor(qq,  off);
    }
    if (l == 0) {
        float den = sqrtf(qq + DEPS) * sqrtf(ssqp[0] + DEPS);
        outp[b] = num / den;
    }
}

// ---------------------------------------------------------------- launcher
extern "C" void kernel_launch(void* const* d_in, const int* in_sizes, int n_in,
                              void* d_out, int out_size, void* d_ws, size_t ws_size,
                              hipStream_t stream) {
    const int* query      = (const int*)d_in[0];
    const int* support    = (const int*)d_in[1];
    const int* q_l1       = (const int*)d_in[2];
    const int* q_deg_l    = (const int*)d_in[3];
    const int* q_r1       = (const int*)d_in[4];
    const int* q_deg_r    = (const int*)d_in[5];
    const int* s_l1       = (const int*)d_in[6];
    const int* s_deg_l    = (const int*)d_in[7];
    const int* s_r1       = (const int*)d_in[8];
    const int* s_deg_r    = (const int*)d_in[9];
    const float* sym      = (const float*)d_in[10];
    const float* gcn_w_W  = (const float*)d_in[11];
    const float* gcn_w_b  = (const float*)d_in[12];
    const float* gcn_b    = (const float*)d_in[13];
    const float* gate_w   = (const float*)d_in[14];
    const float* gtemp    = (const float*)d_in[15];
    const float* se_W1    = (const float*)d_in[16];
    const float* se_b1    = (const float*)d_in[17];
    const float* se_W2    = (const float*)d_in[18];
    const float* se_b2    = (const float*)d_in[19];
    const float* ln_g     = (const float*)d_in[20];
    const float* ln_b     = (const float*)d_in[21];
    const float* lstm_Wih = (const float*)d_in[22];
    const float* lstm_Whh = (const float*)d_in[23];
    const float* lstm_bih = (const float*)d_in[24];
    const float* lstm_bhh = (const float*)d_in[25];

    float* ws    = (float*)d_ws;
    float* qvec  = ws;                      // 4096*256 (h0 alias after se)
    float* qenc  = qvec  + 1048576;         // 4096*256
    float* h1    = qenc  + 1048576;         // 4096*256: parks wT/w1T/w2T
    float* cbuf  = h1    + 1048576;         // 4096*512
    float* svec  = cbuf  + 2097152;         // 5*256
    float* senc  = svec  + 1280;            // 5*256
    float* supg  = senc  + 1280;            // 256
    float* supc0 = supg  + 256;             // 2048
    float* supc  = supc0 + 2048;            // 2048
    float* ssqp  = supc  + 2048;            // 1 (+pad to 64)
    float* wT    = h1;                      // 256*128 (dead after ne)
    float* w1T   = h1 + 32768;              // 256*512 (dead after se)
    float* w2T   = h1 + 163840;             // 512*256 (dead after se)
    float* h0    = qvec;                    // alias
    // bf16 area (aligned region beyond 21 MB)
    float* bfbase = ssqp + 64;
    u16* Abf  = (u16*)bfbase;               // 4096*512 bf16 = 4 MB
    u16* Wcat = Abf + 2097152;              // 2048*512 bf16 = 2 MB
    u16* gates= Wcat + 1048576;             // 4096*2048 bf16 = 16 MB
    // total ws use ~= 43.1 MB

    transpose_f32<<<128, 256, 0, stream>>>(gcn_w_W, wT, 128, 256);
    transpose_f32<<<512, 256, 0, stream>>>(se_W1, w1T, 512, 256);
    transpose_f32<<<512, 256, 0, stream>>>(se_W2, w2T, 256, 512);

    ne_kernel<<<8202, 256, 0, stream>>>(
        sym, wT, gcn_w_b, gcn_b, gate_w, gtemp,
        query, support, q_l1, q_r1, s_l1, s_r1,
        q_deg_l, q_deg_r, s_deg_l, s_deg_r, qvec, svec);

    se_kernel<<<1026, 256, 0, stream>>>(
        qvec, svec, w1T, w2T, se_b1, se_b2, ln_g, ln_b, qenc, senc);

    prep_kernel<<<8192, 256, 0, stream>>>(qenc, lstm_Wih, lstm_Whh, Abf, Wcat);
    supg_kernel<<<1, 256, 0, stream>>>(senc, supg, ssqp);
    supc_kernel<<<32, 256, 0, stream>>>(supg, lstm_Whh, lstm_bih, lstm_bhh, supc0, supc);

    for (int s = 0; s < 4; ++s) {
        lstm_mfma<<<dim3(64, 32), 256, 0, stream>>>(Abf, Wcat, gates, s == 0 ? 256 : 512);
        lstm_elem<<<8192, 256, 0, stream>>>(gates, s == 0 ? supc0 : supc,
                                            cbuf, qenc, Abf, h0, s);
    }

    final_kernel<<<1024, 256, 0, stream>>>(h0, supg, ssqp, (float*)d_out);
}

// Round 6
// 695.031 us; speedup vs baseline: 3.0710x; 1.2187x over previous
//
#include <hip/hip_runtime.h>

#define PADID  100000
#define DEPS   1e-8f
#define LNEPS  1e-5f

typedef unsigned short u16;
typedef unsigned int u32;
typedef __attribute__((ext_vector_type(8))) short s16x8;   // 8 bf16 = 4 VGPR
typedef __attribute__((ext_vector_type(4))) float f32x4;

__device__ __forceinline__ float sigm(float x) { return 1.f / (1.f + expf(-x)); }
__device__ __forceinline__ float bf2f(u16 v) { return __uint_as_float(((u32)v) << 16); }
__device__ __forceinline__ u16 f2bf(float f) {            // RNE f32->bf16
    u32 x = __float_as_uint(f);
    x += 0x7FFFu + ((x >> 16) & 1u);
    return (u16)(x >> 16);
}

// ---------------------------------------------------------------- transpose (f32)
__global__ void transpose_f32(const float* __restrict__ src, float* __restrict__ dst,
                              int R, int C) {
    int idx = blockIdx.x * 256 + threadIdx.x;
    if (idx < R * C) {
        int r = idx / C, c = idx - r * C;
        dst[c * R + r] = src[idx];
    }
}

// ---------------------------------------------------------------- W 3-way bf16 split
__global__ void wsplit_kernel(const float* __restrict__ W, u16* __restrict__ wh,
                              u16* __restrict__ wm, u16* __restrict__ wl) {
    int idx = blockIdx.x * 256 + threadIdx.x;      // 128*256 = 32768
    float x = W[idx];
    u16 h = f2bf(x);  float hf = __uint_as_float((u32)h << 16);
    float r1 = x - hf;
    u16 m = f2bf(r1); float mf = __uint_as_float((u32)m << 16);
    u16 l2 = f2bf(r1 - mf);
    wh[idx] = h; wm[idx] = m; wl[idx] = l2;
}

// ---------------------------------------------------------------- neighbor encoder (split-bf16 MFMA)
// block = 2 units (unit = (row,side)); 4 waves; per wave 64 rows x 64 cols, 4x4 MFMA reg tile.
// proj = concat[128x256] @ W^T via 6 split-products (hh,hm,mh,hl,lh,mm) ~ f32 precision.
__global__ __launch_bounds__(256) void ne_mfma(
    const float* __restrict__ sym,
    const u16* __restrict__ wh, const u16* __restrict__ wm, const u16* __restrict__ wl,
    const float* __restrict__ wbias, const float* __restrict__ gbias,
    const float* __restrict__ gate_w, const float* __restrict__ gtemp,
    const int* __restrict__ query, const int* __restrict__ support,
    const int* __restrict__ q_l1, const int* __restrict__ q_r1,
    const int* __restrict__ s_l1, const int* __restrict__ s_r1,
    const int* __restrict__ q_deg_l, const int* __restrict__ q_deg_r,
    const int* __restrict__ s_deg_l, const int* __restrict__ s_deg_r,
    float* __restrict__ qvec, float* __restrict__ svec)
{
    __shared__ __align__(16) u16 sAb[3][128 * 64];   // 48 KB, XOR-swizzled (16B granules)
    __shared__ float s_self[2][128];
    __shared__ int   s_idr[128], s_ide[128];
    __shared__ float s_mask[128];
    __shared__ float s_norm[2];
    // post-K aliases into sAb (safe: barrier after last frag read)
    float* s_red  = (float*)&sAb[0][0];      // [2][64][4]: num_w0, nn_w0, num_w1, nn_w1
    float* s_cosA = s_red + 512;             // [2][64]
    int*   s_topk = (int*)(s_cosA + 128);    // [2][10]
    float* s_gate = (float*)(s_topk + 20);   // [2]

    const int t = threadIdx.x;
    const int w = t >> 6, l = t & 63;
    const int fr = l & 15, fq = l >> 4;

    // per-unit params (all threads compute both)
    int selfid[2], deg[2];
    const int* conn[2];
    float* outp[2];
    #pragma unroll
    for (int u = 0; u < 2; ++u) {
        int gu = blockIdx.x * 2 + u;
        int row = gu >> 1, side = gu & 1;
        if (row < 4096) {
            conn[u]   = (side ? q_r1 : q_l1) + row * 100;
            deg[u]    = (side ? q_deg_r : q_deg_l)[row];
            selfid[u] = query[row * 2 + side];
            outp[u]   = qvec + (size_t)row * 256 + side * 128;
        } else {
            int r = row - 4096;
            conn[u]   = (side ? s_r1 : s_l1) + r * 100;
            deg[u]    = (side ? s_deg_r : s_deg_l)[r];
            selfid[u] = support[r * 2 + side];
            outp[u]   = svec + (size_t)r * 256 + side * 128;
        }
    }

    // stage ids + pad-mask + self embedding
    if (t < 128) {
        int u = t >> 6, jj = t & 63;
        int ir = 0, ie = 0; float mk = 0.f;
        if (jj < 50) {
            ir = conn[u][2 * jj]; ie = conn[u][2 * jj + 1];
            mk = (ir == PADID) ? 0.f : 1.f;
        }
        s_idr[t] = ir; s_ide[t] = ie; s_mask[t] = mk;
    }
    { int u = t >> 7, d = t & 127;
      s_self[u][d] = sym[(size_t)selfid[u] * 128 + d]; }
    if (w < 2) {                         // self-norm, waves 0/1 -> units 0/1
        float a = s_self[w][l], b = s_self[w][l + 64];
        float s2 = a * a + b * b;
        #pragma unroll
        for (int off = 32; off; off >>= 1) s2 += __shfl_xor(s2, off);
        if (l == 0) s_norm[w] = s2;
    }

    f32x4 acc[4][4];
    #pragma unroll
    for (int mt = 0; mt < 4; ++mt)
        #pragma unroll
        for (int nt = 0; nt < 4; ++nt)
            acc[mt][nt] = (f32x4){0.f, 0.f, 0.f, 0.f};

    const int rbase = (w >> 1) * 64;     // unit = w>>1
    const int cbase = (w & 1) * 64;
    const u16* wt0[3] = {wh, wm, wl};

    for (int c = 0; c < 4; ++c) {        // K chunks of 64 (0,1: rel; 2,3: ent)
        __syncthreads();
        #pragma unroll
        for (int i = 0; i < 4; ++i) {    // stage+decompose: 1024 granules / 256 thr
            int seg = i * 256 + t;
            int r = seg >> 3, kc = seg & 7;
            int id = (c < 2) ? s_idr[r] : s_ide[r];
            int scol = (c & 1) * 64 + kc * 8;
            const float* src = sym + (size_t)id * 128 + scol;
            float x[8];
            *(float4*)&x[0] = *(const float4*)src;
            *(float4*)&x[4] = *(const float4*)(src + 4);
            u16 hh_[8], mm_[8], ll_[8];
            #pragma unroll
            for (int e = 0; e < 8; ++e) {
                float xv = x[e];
                u16 h = f2bf(xv);  float hf = __uint_as_float((u32)h << 16);
                float r1 = xv - hf;
                u16 m = f2bf(r1);  float mf = __uint_as_float((u32)m << 16);
                u16 l2 = f2bf(r1 - mf);
                hh_[e] = h; mm_[e] = m; ll_[e] = l2;
            }
            int didx = r * 64 + ((kc ^ (r & 7)) * 8);
            uint4 ph, pm, pl;
            ph.x = hh_[0] | ((u32)hh_[1] << 16); ph.y = hh_[2] | ((u32)hh_[3] << 16);
            ph.z = hh_[4] | ((u32)hh_[5] << 16); ph.w = hh_[6] | ((u32)hh_[7] << 16);
            pm.x = mm_[0] | ((u32)mm_[1] << 16); pm.y = mm_[2] | ((u32)mm_[3] << 16);
            pm.z = mm_[4] | ((u32)mm_[5] << 16); pm.w = mm_[6] | ((u32)mm_[7] << 16);
            pl.x = ll_[0] | ((u32)ll_[1] << 16); pl.y = ll_[2] | ((u32)ll_[3] << 16);
            pl.z = ll_[4] | ((u32)ll_[5] << 16); pl.w = ll_[6] | ((u32)ll_[7] << 16);
            *(uint4*)&sAb[0][didx] = ph;
            *(uint4*)&sAb[1][didx] = pm;
            *(uint4*)&sAb[2][didx] = pl;
        }
        __syncthreads();
        #pragma unroll
        for (int s2 = 0; s2 < 2; ++s2) { // k-steps of 32
            int gnu = s2 * 4 + fq;       // A granule
            int kin = c * 64 + s2 * 32 + fq * 8;
            #pragma unroll
            for (int sb = 0; sb < 3; ++sb) {
                s16x8 bfr[4];
                #pragma unroll
                for (int nt = 0; nt < 4; ++nt) {
                    int col = cbase + nt * 16 + fr;
                    bfr[nt] = *(const s16x8*)(wt0[sb] + (size_t)col * 256 + kin);
                }
                #pragma unroll
                for (int sa = 0; sa < 3 - sb; ++sa) {   // products: hh,mh,lh | hm,mm | hl
                    s16x8 af[4];
                    #pragma unroll
                    for (int mt = 0; mt < 4; ++mt) {
                        int rowi = rbase + mt * 16 + fr;
                        af[mt] = *(const s16x8*)&sAb[sa][rowi * 64 + ((gnu ^ (rowi & 7)) * 8)];
                    }
                    #pragma unroll
                    for (int mt = 0; mt < 4; ++mt)
                        #pragma unroll
                        for (int nt = 0; nt < 4; ++nt)
                            acc[mt][nt] = __builtin_amdgcn_mfma_f32_16x16x32_bf16(
                                af[mt], bfr[nt], acc[mt][nt], 0, 0, 0);
                }
            }
        }
    }
    __syncthreads();   // all frag reads done -> alias region writable

    const int u = w >> 1;
    // bias + leaky-relu + mask (in regs)
    float biasc[4], sfv[4];
    #pragma unroll
    for (int nt = 0; nt < 4; ++nt) {
        int jc = cbase + nt * 16 + fr;
        biasc[nt] = wbias[jc] + gbias[jc];
        sfv[nt]   = s_self[u][jc];
    }
    float msk[4][4];
    #pragma unroll
    for (int mt = 0; mt < 4; ++mt)
        #pragma unroll
        for (int rr = 0; rr < 4; ++rr)
            msk[mt][rr] = s_mask[rbase + mt * 16 + fq * 4 + rr];
    #pragma unroll
    for (int mt = 0; mt < 4; ++mt)
        #pragma unroll
        for (int nt = 0; nt < 4; ++nt)
            #pragma unroll
            for (int rr = 0; rr < 4; ++rr) {
                float v = acc[mt][nt][rr] + biasc[nt];
                v = (v > 0.f) ? v : 0.01f * v;
                acc[mt][nt][rr] = v * msk[mt][rr];
            }

    // cosine partials: reduce 4 cols/lane over the 16 fr-lanes
    #pragma unroll
    for (int mt = 0; mt < 4; ++mt)
        #pragma unroll
        for (int rr = 0; rr < 4; ++rr) {
            float np_ = 0.f, nn_ = 0.f;
            #pragma unroll
            for (int nt = 0; nt < 4; ++nt) {
                float v = acc[mt][nt][rr];
                np_ += v * sfv[nt];
                nn_ += v * v;
            }
            np_ += __shfl_xor(np_, 1); nn_ += __shfl_xor(nn_, 1);
            np_ += __shfl_xor(np_, 2); nn_ += __shfl_xor(nn_, 2);
            np_ += __shfl_xor(np_, 4); nn_ += __shfl_xor(nn_, 4);
            np_ += __shfl_xor(np_, 8); nn_ += __shfl_xor(nn_, 8);
            if (fr == 0) {
                int j = mt * 16 + fq * 4 + rr;
                float* rp = s_red + (u * 64 + j) * 4 + (w & 1) * 2;
                rp[0] = np_; rp[1] = nn_;
            }
        }
    __syncthreads();

    if (t < 128) {   // combine wave halves -> cos
        int uu = t >> 6;
        float num = s_red[t * 4 + 0] + s_red[t * 4 + 2];
        float nn  = s_red[t * 4 + 1] + s_red[t * 4 + 3];
        float ns  = sqrtf(s_norm[uu] + DEPS);
        s_cosA[t] = num / (ns * sqrtf(nn + DEPS) + DEPS);
    }
    __syncthreads();

    if ((w & 1) == 0) {      // waves 0,2: top-10 (value desc, index asc)
        int uu = w >> 1;
        float myv = (l < 50) ? s_cosA[uu * 64 + l] : -3.4e38f;
        int live  = (l < 50) ? 1 : 0;
        for (int m = 0; m < 10; ++m) {
            float bv = live ? myv : -3.4e38f;
            int   bi = l;
            #pragma unroll
            for (int off = 1; off < 64; off <<= 1) {
                float ov = __shfl_xor(bv, off);
                int   oi = __shfl_xor(bi, off);
                if (ov > bv || (ov == bv && oi < bi)) { bv = ov; bi = oi; }
            }
            if (bi == l) live = 0;
            if (l == 0) s_topk[uu * 10 + m] = bi;
        }
    } else {                 // waves 1,3: gate
        int uu = w >> 1;
        float g = 0.f;
        if (l < 50) {
            int r = s_idr[uu * 64 + l];
            g = gate_w[(r == PADID) ? 0 : r];
        }
        #pragma unroll
        for (int off = 32; off; off >>= 1) g += __shfl_xor(g, off);
        if (l == 0) {
            float gate = sigm((g / 50.f) / gtemp[0]);
            if (deg[uu] <= 0) gate = 1.f;
            s_gate[uu] = gate;
        }
    }
    __syncthreads();

    // agg over top-10 + output
    {
        bool sel[4][4];
        #pragma unroll
        for (int mt = 0; mt < 4; ++mt)
            #pragma unroll
            for (int rr = 0; rr < 4; ++rr) sel[mt][rr] = false;
        #pragma unroll
        for (int i2 = 0; i2 < 10; ++i2) {
            int tj = s_topk[u * 10 + i2];
            #pragma unroll
            for (int mt = 0; mt < 4; ++mt)
                #pragma unroll
                for (int rr = 0; rr < 4; ++rr)
                    sel[mt][rr] = sel[mt][rr] | (mt * 16 + fq * 4 + rr == tj);
        }
        float ag[4] = {0.f, 0.f, 0.f, 0.f};
        #pragma unroll
        for (int mt = 0; mt < 4; ++mt)
            #pragma unroll
            for (int rr = 0; rr < 4; ++rr)
                if (sel[mt][rr]) {
                    #pragma unroll
                    for (int nt = 0; nt < 4; ++nt) ag[nt] += acc[mt][nt][rr];
                }
        #pragma unroll
        for (int nt = 0; nt < 4; ++nt) {
            ag[nt] += __shfl_xor(ag[nt], 16);
            ag[nt] += __shfl_xor(ag[nt], 32);
        }
        if (fq == 0) {
            float gate = s_gate[u];
            #pragma unroll
            for (int nt = 0; nt < 4; ++nt) {
                int jc = cbase + nt * 16 + fr;
                outp[u][jc] = tanhf(s_self[u][jc] + gate * ag[nt] * 0.1f);
            }
        }
    }
}

// ---------------------------------------------------------------- support encoder
#define SE_ROWS 4
__global__ __launch_bounds__(256) void se_kernel(
    const float* __restrict__ qvec, const float* __restrict__ svec,
    const float* __restrict__ w1T, const float* __restrict__ w2T,
    const float* __restrict__ b1, const float* __restrict__ b2,
    const float* __restrict__ lng, const float* __restrict__ lnb,
    float* __restrict__ qenc, float* __restrict__ senc)
{
    const int t  = threadIdx.x;
    const int r0 = blockIdx.x * SE_ROWS;

    __shared__ float sx[SE_ROWS][256];
    __shared__ float shid[SE_ROWS][512];
    __shared__ float sred[4][SE_ROWS][2];

    for (int idx = t; idx < SE_ROWS * 64; idx += 256) {
        int r = idx >> 6, k4 = (idx & 63) * 4;
        int row = r0 + r;
        float4 v = make_float4(0.f, 0.f, 0.f, 0.f);
        if (row < 4101) {
            const float* x = (row < 4096) ? (qvec + (size_t)row * 256)
                                          : (svec + (size_t)(row - 4096) * 256);
            v = *(const float4*)&x[k4];
        }
        *(float4*)&sx[r][k4] = v;
    }
    __syncthreads();

    float h[2][SE_ROWS];
    {
        float bb0 = b1[t], bb1 = b1[t + 256];
        #pragma unroll
        for (int r = 0; r < SE_ROWS; ++r) { h[0][r] = bb0; h[1][r] = bb1; }
    }
    for (int k = 0; k < 256; ++k) {
        float w0 = w1T[k * 512 + t];
        float w1 = w1T[k * 512 + t + 256];
        #pragma unroll
        for (int r = 0; r < SE_ROWS; ++r) {
            float xv = sx[r][k];
            h[0][r] += xv * w0;
            h[1][r] += xv * w1;
        }
    }
    #pragma unroll
    for (int r = 0; r < SE_ROWS; ++r) {
        shid[r][t]       = fmaxf(h[0][r], 0.f);
        shid[r][t + 256] = fmaxf(h[1][r], 0.f);
    }
    __syncthreads();

    float acc2[SE_ROWS];
    {
        float bb = b2[t];
        #pragma unroll
        for (int r = 0; r < SE_ROWS; ++r) acc2[r] = bb + sx[r][t];
    }
    for (int k = 0; k < 512; ++k) {
        float w = w2T[k * 256 + t];
        #pragma unroll
        for (int r = 0; r < SE_ROWS; ++r) acc2[r] += shid[r][k] * w;
    }

    int wv = t >> 6;
    #pragma unroll
    for (int r = 0; r < SE_ROWS; ++r) {
        float s = acc2[r], q = acc2[r] * acc2[r];
        #pragma unroll
        for (int off = 32; off; off >>= 1) {
            s += __shfl_xor(s, off);
            q += __shfl_xor(q, off);
        }
        if ((t & 63) == 0) { sred[wv][r][0] = s; sred[wv][r][1] = q; }
    }
    __syncthreads();
    float gv = lng[t], bv = lnb[t];
    #pragma unroll
    for (int r = 0; r < SE_ROWS; ++r) {
        int row = r0 + r;
        if (row < 4101) {
            float S = sred[0][r][0] + sred[1][r][0] + sred[2][r][0] + sred[3][r][0];
            float Q = sred[0][r][1] + sred[1][r][1] + sred[2][r][1] + sred[3][r][1];
            float mu  = S / 256.f;
            float var = Q / 256.f - mu * mu;
            float o = gv * (acc2[r] - mu) / sqrtf(var + LNEPS) + bv;
            float* op = (row < 4096) ? (qenc + (size_t)row * 256)
                                     : (senc + (size_t)(row - 4096) * 256);
            op[t] = o;
        }
    }
}

// ---------------------------------------------------------------- support mean
__global__ __launch_bounds__(256) void supg_kernel(
    const float* __restrict__ senc, float* __restrict__ supg,
    float* __restrict__ ssqp)
{
    int t = threadIdx.x;
    __shared__ float sr[4];
    float m = (senc[t] + senc[256 + t] + senc[512 + t] + senc[768 + t] + senc[1024 + t]) * 0.2f;
    supg[t] = m;
    float sq = m * m;
    #pragma unroll
    for (int off = 32; off; off >>= 1) sq += __shfl_xor(sq, off);
    if ((t & 63) == 0) sr[t >> 6] = sq;
    __syncthreads();
    if (t == 0) ssqp[0] = sr[0] + sr[1] + sr[2] + sr[3];
}

// ---------------------------------------------------------------- supc
__global__ __launch_bounds__(256) void supc_kernel(
    const float* __restrict__ supg, const float* __restrict__ Whh,
    const float* __restrict__ bih, const float* __restrict__ bhh,
    float* __restrict__ supc0, float* __restrict__ supc)
{
    const int t = threadIdx.x, w = t >> 6, l = t & 63;
    __shared__ float sg[256];
    if (t < 256) sg[t] = supg[t];
    __syncthreads();
    float4 gv = *(const float4*)&sg[l * 4];
    #pragma unroll
    for (int jj = 0; jj < 16; ++jj) {
        int j = blockIdx.x * 64 + w * 16 + jj;
        float4 wv = *(const float4*)&Whh[(size_t)j * 512 + 256 + l * 4];
        float p = gv.x * wv.x + gv.y * wv.y + gv.z * wv.z + gv.w * wv.w;
        #pragma unroll
        for (int off = 32; off; off >>= 1) p += __shfl_xor(p, off);
        if (l == 0) {
            float c0 = bih[j] + bhh[j];
            supc0[j] = c0;
            supc[j]  = c0 + p;
        }
    }
}

// ---------------------------------------------------------------- bf16 prep
__global__ __launch_bounds__(256) void prep_kernel(
    const float* __restrict__ qenc, const float* __restrict__ Wih,
    const float* __restrict__ Whh, u16* __restrict__ Abf, u16* __restrict__ Wcat)
{
    int idx = blockIdx.x * 256 + threadIdx.x;
    if (idx < 1048576) {
        int m = idx >> 8, k = idx & 255;
        Abf[(size_t)m * 512 + k] = f2bf(qenc[idx]);
    } else if (idx < 1572864) {
        int i = idx - 1048576;
        int n = i >> 8, k = i & 255;
        Wcat[(size_t)n * 512 + k] = f2bf(Wih[i]);
    } else {
        int i = idx - 1572864;
        int n = i >> 8, k = i & 255;
        Wcat[(size_t)n * 512 + 256 + k] = f2bf(Whh[(size_t)n * 512 + k]);
    }
}

// ---------------------------------------------------------------- LSTM gate GEMM (bf16 MFMA)
__global__ __launch_bounds__(256) void lstm_mfma(
    const u16* __restrict__ A, const u16* __restrict__ B,
    u16* __restrict__ C, int Klen)
{
    __shared__ u16 sA[64][72];
    __shared__ u16 sB[64][72];
    const int t    = threadIdx.x;
    const int wid  = t >> 6;
    const int lane = t & 63;
    const int m0   = blockIdx.x * 64;
    const int n0   = blockIdx.y * 64;
    const int mw   = (wid & 1) * 32;
    const int nw   = (wid >> 1) * 32;
    const int r    = t >> 2;
    const int q    = t & 3;
    const int fr   = lane & 15;
    const int fk   = (lane >> 4) * 8;

    f32x4 acc[2][2];
    #pragma unroll
    for (int i = 0; i < 2; ++i)
        #pragma unroll
        for (int j = 0; j < 2; ++j)
            acc[i][j] = (f32x4){0.f, 0.f, 0.f, 0.f};

    for (int k0 = 0; k0 < Klen; k0 += 64) {
        const u16* ga = A + (size_t)(m0 + r) * 512 + k0 + q * 16;
        const u16* gb = B + (size_t)(n0 + r) * 512 + k0 + q * 16;
        uint4 va0 = *(const uint4*)ga;
        uint4 va1 = *(const uint4*)(ga + 8);
        uint4 vb0 = *(const uint4*)gb;
        uint4 vb1 = *(const uint4*)(gb + 8);
        __syncthreads();
        *(uint4*)&sA[r][q * 16]     = va0;
        *(uint4*)&sA[r][q * 16 + 8] = va1;
        *(uint4*)&sB[r][q * 16]     = vb0;
        *(uint4*)&sB[r][q * 16 + 8] = vb1;
        __syncthreads();
        #pragma unroll
        for (int ks = 0; ks < 64; ks += 32) {
            s16x8 af[2], bf[2];
            #pragma unroll
            for (int i = 0; i < 2; ++i)
                af[i] = *(const s16x8*)&sA[mw + i * 16 + fr][ks + fk];
            #pragma unroll
            for (int j = 0; j < 2; ++j)
                bf[j] = *(const s16x8*)&sB[nw + j * 16 + fr][ks + fk];
            #pragma unroll
            for (int i = 0; i < 2; ++i)
                #pragma unroll
                for (int j = 0; j < 2; ++j)
                    acc[i][j] = __builtin_amdgcn_mfma_f32_16x16x32_bf16(
                        af[i], bf[j], acc[i][j], 0, 0, 0);
        }
    }

    #pragma unroll
    for (int i = 0; i < 2; ++i)
        #pragma unroll
        for (int j = 0; j < 2; ++j) {
            int col = n0 + nw + j * 16 + fr;
            #pragma unroll
            for (int rr = 0; rr < 4; ++rr) {
                int rowi = m0 + mw + i * 16 + (lane >> 4) * 4 + rr;
                C[(size_t)rowi * 2048 + col] = f2bf(acc[i][j][rr]);
            }
        }
}

// ---------------------------------------------------------------- LSTM elementwise
__global__ __launch_bounds__(256) void lstm_elem(
    const u16* __restrict__ gates, const float* __restrict__ cvec,
    float* __restrict__ cbuf, const float* __restrict__ qenc,
    u16* __restrict__ Abf, float* __restrict__ hfinal, int step)
{
    int idx = blockIdx.x * 256 + threadIdx.x;
    int m = idx >> 9, j = idx & 511;
    const u16* g = gates + (size_t)m * 2048;
    float iv = bf2f(g[j])        + cvec[j];
    float fv = bf2f(g[512 + j])  + cvec[512 + j];
    float gv = bf2f(g[1024 + j]) + cvec[1024 + j];
    float ov = bf2f(g[1536 + j]) + cvec[1536 + j];
    float cold = (step == 0) ? 0.f : cbuf[idx];
    float cn = sigm(fv) * cold + sigm(iv) * tanhf(gv);
    cbuf[idx] = cn;
    if (j < 256) {
        float hn = sigm(ov) * tanhf(cn);
        float h  = qenc[(size_t)m * 256 + j] + hn;
        Abf[(size_t)m * 512 + 256 + j] = f2bf(h);
        if (step == 3) hfinal[(size_t)m * 256 + j] = h;
    }
}

// ---------------------------------------------------------------- final cosine
__global__ __launch_bounds__(256) void final_kernel(
    const float* __restrict__ h, const float* __restrict__ supg,
    const float* __restrict__ ssqp, float* __restrict__ outp)
{
    int t = threadIdx.x;
    int w = t >> 6, l = t & 63;
    int b = blockIdx.x * 4 + w;
    float4 q = *(const float4*)&h[b * 256 + l * 4];
    float4 s = *(const float4*)&supg[l * 4];
    float num = q.x * s.x + q.y * s.y + q.z * s.z + q.w * s.w;
    float qq  = q.x * q.x + q.y * q.y + q.z * q.z + q.w * q.w;
    #pragma unroll
    for (int off = 32; off; off >>= 1) {
        num += __shfl_xor(num, off);
        qq  += __shfl_xor(qq,  off);
    }
    if (l == 0) {
        float den = sqrtf(qq + DEPS) * sqrtf(ssqp[0] + DEPS);
        outp[b] = num / den;
    }
}

// ---------------------------------------------------------------- launcher
extern "C" void kernel_launch(void* const* d_in, const int* in_sizes, int n_in,
                              void* d_out, int out_size, void* d_ws, size_t ws_size,
                              hipStream_t stream) {
    const int* query      = (const int*)d_in[0];
    const int* support    = (const int*)d_in[1];
    const int* q_l1       = (const int*)d_in[2];
    const int* q_deg_l    = (const int*)d_in[3];
    const int* q_r1       = (const int*)d_in[4];
    const int* q_deg_r    = (const int*)d_in[5];
    const int* s_l1       = (const int*)d_in[6];
    const int* s_deg_l    = (const int*)d_in[7];
    const int* s_r1       = (const int*)d_in[8];
    const int* s_deg_r    = (const int*)d_in[9];
    const float* sym      = (const float*)d_in[10];
    const float* gcn_w_W  = (const float*)d_in[11];
    const float* gcn_w_b  = (const float*)d_in[12];
    const float* gcn_b    = (const float*)d_in[13];
    const float* gate_w   = (const float*)d_in[14];
    const float* gtemp    = (const float*)d_in[15];
    const float* se_W1    = (const float*)d_in[16];
    const float* se_b1    = (const float*)d_in[17];
    const float* se_W2    = (const float*)d_in[18];
    const float* se_b2    = (const float*)d_in[19];
    const float* ln_g     = (const float*)d_in[20];
    const float* ln_b     = (const float*)d_in[21];
    const float* lstm_Wih = (const float*)d_in[22];
    const float* lstm_Whh = (const float*)d_in[23];
    const float* lstm_bih = (const float*)d_in[24];
    const float* lstm_bhh = (const float*)d_in[25];

    float* ws    = (float*)d_ws;
    float* qvec  = ws;                      // 4096*256 (h0 alias)
    float* qenc  = qvec  + 1048576;
    float* h1    = qenc  + 1048576;         // parks w1T/w2T
    float* cbuf  = h1    + 1048576;
    float* svec  = cbuf  + 2097152;
    float* senc  = svec  + 1280;
    float* supg  = senc  + 1280;
    float* supc0 = supg  + 256;
    float* supc  = supc0 + 2048;
    float* ssqp  = supc  + 2048;
    float* w1T   = h1;                      // 131072
    float* w2T   = h1 + 131072;             // 131072
    float* h0    = qvec;
    float* bfbase = ssqp + 64;
    u16* Abf   = (u16*)bfbase;              // 4096*512
    u16* Wcat  = Abf + 2097152;             // 2048*512
    u16* gates = Wcat + 1048576;            // 4096*2048
    u16* wh    = gates + 8388608;           // 128*256 each
    u16* wmS   = wh + 32768;
    u16* wlS   = wmS + 32768;
    // total ws ~= 43.3 MB

    transpose_f32<<<512, 256, 0, stream>>>(se_W1, w1T, 512, 256);
    transpose_f32<<<512, 256, 0, stream>>>(se_W2, w2T, 256, 512);
    wsplit_kernel<<<128, 256, 0, stream>>>(gcn_w_W, wh, wmS, wlS);

    ne_mfma<<<4101, 256, 0, stream>>>(
        sym, wh, wmS, wlS, gcn_w_b, gcn_b, gate_w, gtemp,
        query, support, q_l1, q_r1, s_l1, s_r1,
        q_deg_l, q_deg_r, s_deg_l, s_deg_r, qvec, svec);

    se_kernel<<<1026, 256, 0, stream>>>(
        qvec, svec, w1T, w2T, se_b1, se_b2, ln_g, ln_b, qenc, senc);

    prep_kernel<<<8192, 256, 0, stream>>>(qenc, lstm_Wih, lstm_Whh, Abf, Wcat);
    supg_kernel<<<1, 256, 0, stream>>>(senc, supg, ssqp);
    supc_kernel<<<32, 256, 0, stream>>>(supg, lstm_Whh, lstm_bih, lstm_bhh, supc0, supc);

    for (int s = 0; s < 4; ++s) {
        lstm_mfma<<<dim3(64, 32), 256, 0, stream>>>(Abf, Wcat, gates, s == 0 ? 256 : 512);
        lstm_elem<<<8192, 256, 0, stream>>>(gates, s == 0 ? supc0 : supc,
                                            cbuf, qenc, Abf, h0, s);
    }

    final_kernel<<<1024, 256, 0, stream>>>(h0, supg, ssqp, (float*)d_out);
}